// Round 11
// baseline (411.616 us; speedup 1.0000x reference)
//
#include <hip/hip_runtime.h>
#include <math.h>

// Problem constants (B=1 fixed by reference)
#define NP 9216          // S*S spatial positions
#define DC 256           // channels
#define DN (DC * NP)
#define TB 256           // ksim block tile
#define NTT 36           // 9216 / 256 tiles per dim
#define KCH (NP * 32)    // halves per k-chunk section of a plane

#define FEPS 2.220446049250313e-16f

typedef __attribute__((ext_vector_type(8))) _Float16 half8v;
typedef __attribute__((ext_vector_type(4))) float   float4v;

union HU { _Float16 h; unsigned short u; };
__device__ __forceinline__ unsigned short f2h(float f) { HU x; x.h = (_Float16)f; return x.u; }
__device__ __forceinline__ float h2f(unsigned short s) { HU x; x.u = s; return (float)x.h; }

// async global->LDS, 16B/lane, no VGPR round-trip. LDS dest must be
// wave-uniform base + lane*16 — staging maps below are flat t*16.
__device__ __forceinline__ void gload16(const void* g, void* l)
{
    __builtin_amdgcn_global_load_lds(
        (const __attribute__((address_space(1))) unsigned int*)g,
        (__attribute__((address_space(3))) unsigned int*)l,
        16, 0, 0);
}

// Plane layout (k-major): half index off(n,k) = (k>>5)*KCH + n*32 + (k&31).

// ---------------- Kernel 1: fused normalize + fp16 split ----------------
// Split: H = fp16(v*2^8); L = fp16((v*2^8 - H)*2^11) (exact residual).
__global__ __launch_bounds__(256) void kprep(
    const float* __restrict__ X, const float* __restrict__ Y,
    float* __restrict__ Xf_out,
    unsigned short* __restrict__ XH, unsigned short* __restrict__ XL,
    unsigned short* __restrict__ YH, unsigned short* __restrict__ YL,
    float* __restrict__ lacc)
{
    __shared__ float tile[64 * 257];   // (n, d) at n*257+d
    __shared__ float psum[4][64];
    __shared__ float invs[64];

    const int t = threadIdx.x;
    const bool isX = (blockIdx.y == 0);
    const float* src = isX ? X : Y;
    unsigned* hT = (unsigned*)(isX ? XH : YH);
    unsigned* lT = (unsigned*)(isX ? XL : YL);
    const int n0 = blockIdx.x * 64;

    if (blockIdx.x == 0 && blockIdx.y == 0 && t == 0) *lacc = 0.0f;

    const int lane = t & 63;
    const int w    = t >> 6;      // wave id -> owns d-range [w*64, w*64+64)

    #pragma unroll 8
    for (int i = 0; i < 64; ++i) {
        int d = w * 64 + i;
        tile[lane * 257 + d] = src[(size_t)d * NP + n0 + lane];
    }
    float s = 0.0f;
    #pragma unroll 8
    for (int i = 0; i < 64; ++i) {
        float v = tile[lane * 257 + w * 64 + i];
        s = fmaf(v, v, s);
    }
    psum[w][lane] = s;
    __syncthreads();
    if (t < 64) {
        float tot = psum[0][t] + psum[1][t] + psum[2][t] + psum[3][t];
        invs[t] = 1.0f / (sqrtf(tot) + FEPS);
    }
    __syncthreads();

    // plane writes, k-major layout; coalesced uints.
    for (int kt = 0; kt < 8; ++kt) {
        #pragma unroll
        for (int p = 0; p < 4; ++p) {
            int idx = p * 256 + t;
            int n = idx >> 4;          // 0..63
            int u = idx & 15;          // uint within chunk (2 halves)
            float inv = invs[n];
            int d = kt * 32 + 2 * u;
            float v0 = tile[n * 257 + d] * inv;
            float v1 = tile[n * 257 + d + 1] * inv;
            float s0 = v0 * 256.0f, s1 = v1 * 256.0f;
            unsigned short h0 = f2h(s0), h1 = f2h(s1);
            unsigned short l0 = f2h((s0 - h2f(h0)) * 2048.0f);
            unsigned short l1 = f2h((s1 - h2f(h1)) * 2048.0f);
            size_t uo = (size_t)kt * (NP * 16) + (size_t)(n0 + n) * 16 + u;
            hT[uo] = (unsigned)h0 | ((unsigned)h1 << 16);
            lT[uo] = (unsigned)l0 | ((unsigned)l1 << 16);
        }
    }

    // exact fp32 Xf output ([d][n], coalesced over n)
    if (isX) {
        const float inv = invs[lane];
        #pragma unroll 8
        for (int i = 0; i < 64; ++i) {
            int d = w * 64 + i;
            Xf_out[(size_t)d * NP + n0 + lane] = tile[lane * 257 + d] * inv;
        }
    }
}

// ---------------- Kernel 2: MFMA sim-GEMM + fused per-row argmax ----------
// R11: 256x256 tile, 1024 threads (16 waves, 4x4 of 64x64), BK=32, LDS
// double-buffer 2x64 KB (dynamic LDS 128 KB -> 1 block/CU), staging via
// global_load_lds, ONE barrier/kt. Rationale: R8/R10 were pinned at the
// per-CU VMEM delivery ceiling (2.65 GB = 22 B/cyc/CU = 196 us); this
// cuts global traffic 4x (664 MB) and per-kt staging demand (15.5 B/cyc)
// fits under the compute window (4 waves/SIMD x 1059 cyc) — unlike R7's
// 128-tile (35 B/cyc > ceiling -> serialized barriers).
// Chunk-XOR swizzle keeps fragment ds_read_b128s conflict-free while
// staging stays lane-linear. sim*2^16 = Hx·Hy + 2^-11(Hx·Ly + Lx·Hy),
// single acc + per-kt fold (VGPR budget 128 at 1024 thr).
__global__ __launch_bounds__(1024) void ksim(
    const unsigned short* __restrict__ XH, const unsigned short* __restrict__ XL,
    const unsigned short* __restrict__ YH, const unsigned short* __restrict__ YL,
    float* __restrict__ pmax, int* __restrict__ pidx)
{
    extern __shared__ char LB[];   // 2 x 65536

    const int t  = threadIdx.x;    // 0..1023
    const int n0 = blockIdx.x * TB;
    const int m0 = blockIdx.y * TB;

    // ---- staging maps: thread t stages chunk t (16B) of each plane ----
    // chunk c: row m = c>>2, k-quarter q = (c&3)^((m>>1)&3)  (XOR swizzle)
    const int ms = t >> 2;
    const int qs = (t & 3) ^ ((ms >> 1) & 3);
    const unsigned short* gAh = XH + (size_t)(n0 + ms) * 32 + qs * 8;
    const unsigned short* gAl = XL + (size_t)(n0 + ms) * 32 + qs * 8;
    const unsigned short* gBh = YH + (size_t)(m0 + ms) * 32 + qs * 8;
    const unsigned short* gBl = YL + (size_t)(m0 + ms) * 32 + qs * 8;

    char* const dAh = LB + 0     + t * 16;   // plane Ah (16 KB)
    char* const dAl = LB + 16384 + t * 16;   // Al
    char* const dBh = LB + 32768 + t * 16;   // Bh
    char* const dBl = LB + 49152 + t * 16;   // Bl

    // ---- compute-lane maps: 4x4 wave grid, each wave 64x64 ----
    const int L   = t & 63;
    const int wid = t >> 6;
    const int wr  = wid >> 2;          // row band 0..3
    const int wc  = wid & 3;           // col band 0..3
    const int lc  = L & 15;
    const int lq  = L >> 4;

    const int rowA = wr * 64 + lc;
    const int cA   = rowA * 4 + (lq ^ ((rowA >> 1) & 3));   // rb*16 rows: XOR-invariant
    const int rowB = wc * 64 + lc;
    const int cB   = rowB * 4 + (lq ^ ((rowB >> 1) & 3));

    float4v acc[4][4];
    #pragma unroll
    for (int i = 0; i < 4; ++i)
        #pragma unroll
        for (int j = 0; j < 4; ++j)
            acc[i][j] = (float4v){0.f, 0.f, 0.f, 0.f};
    const float4v z4 = (float4v){0.f, 0.f, 0.f, 0.f};
    const float CS = 1.0f / 2048.0f;

    // prologue: stage kt=0 into buffer 0
    gload16(gAh, dAh); gload16(gAl, dAl); gload16(gBh, dBh); gload16(gBl, dBl);
    gAh += KCH; gAl += KCH; gBh += KCH; gBl += KCH;

    int buf = 0;
    for (int kt = 0; kt < 8; ++kt) {
        // drains vmcnt (loads into `buf` done) + all waves done reading
        // the other buffer -> safe to overwrite it below.
        __syncthreads();

        if (kt < 7) {
            const int bo2 = (buf ^ 1) * 65536;
            gload16(gAh, dAh + bo2); gload16(gAl, dAl + bo2);
            gload16(gBh, dBh + bo2); gload16(gBl, dBl + bo2);
            gAh += KCH; gAl += KCH; gBh += KCH; gBl += KCH;
        }

        const char* base = LB + buf * 65536;
        half8v Ah[4], Al[4];
        #pragma unroll
        for (int rb = 0; rb < 4; ++rb) {
            Ah[rb] = *(const half8v*)(base + cA * 16 + rb * 1024);
            Al[rb] = *(const half8v*)(base + 16384 + cA * 16 + rb * 1024);
        }
        #pragma unroll
        for (int cb = 0; cb < 4; ++cb) {
            const half8v Bh = *(const half8v*)(base + 32768 + cB * 16 + cb * 1024);
            const half8v Bl = *(const half8v*)(base + 49152 + cB * 16 + cb * 1024);
            #pragma unroll
            for (int rb = 0; rb < 4; ++rb) {
                float4v tv;
                tv = __builtin_amdgcn_mfma_f32_16x16x32_f16(Al[rb], Bh, z4, 0, 0, 0);
                tv = __builtin_amdgcn_mfma_f32_16x16x32_f16(Ah[rb], Bl, tv, 0, 0, 0);
                acc[rb][cb] = __builtin_amdgcn_mfma_f32_16x16x32_f16(Ah[rb], Bh, acc[rb][cb], 0, 0, 0);
                acc[rb][cb].x = fmaf(tv.x, CS, acc[rb][cb].x);
                acc[rb][cb].y = fmaf(tv.y, CS, acc[rb][cb].y);
                acc[rb][cb].z = fmaf(tv.z, CS, acc[rb][cb].z);
                acc[rb][cb].w = fmaf(tv.w, CS, acc[rb][cb].w);
            }
        }
        buf ^= 1;
    }

    // ---- epilogue: per-row argmax over own 64-col band ----
    // C/D map: col=lane&15, row=lq*4+reg. Scale 2^16 is argmax-invariant.
    float bv[16]; int bc[16];
    #pragma unroll
    for (int s = 0; s < 16; ++s) { bv[s] = -INFINITY; bc[s] = 0; }

    #pragma unroll
    for (int rb = 0; rb < 4; ++rb)
        #pragma unroll
        for (int cb = 0; cb < 4; ++cb) {   // cb ascending = col ascending
            const int col = m0 + wc * 64 + cb * 16 + lc;
            #pragma unroll
            for (int r = 0; r < 4; ++r) {
                float v = acc[rb][cb][r];
                int s = rb * 4 + r;
                if (v > bv[s]) { bv[s] = v; bc[s] = col; }
            }
        }

    // reduce across the 16 lc lanes (xor<16 stays in the quad-group)
    #pragma unroll
    for (int off = 1; off < 16; off <<= 1) {
        #pragma unroll
        for (int s = 0; s < 16; ++s) {
            float ov = __shfl_xor(bv[s], off, 64);
            int   oi = __shfl_xor(bc[s], off, 64);
            if (ov > bv[s] || (ov == bv[s] && oi < bc[s])) { bv[s] = ov; bc[s] = oi; }
        }
    }

    // combine the 4 column bands via LDS -> one slot per tile.
    // band order ascending == col ascending: strict '>' keeps first-max.
    {
        __syncthreads();                  // all K-loop LDS reads done
        float* v4 = (float*)LB;           // [4][256]
        int*   i4 = (int*)(LB + 4096);    // [4][256]
        if (lc == 0) {
            #pragma unroll
            for (int rb = 0; rb < 4; ++rb)
                #pragma unroll
                for (int r = 0; r < 4; ++r) {
                    int rl = wr * 64 + rb * 16 + lq * 4 + r;
                    v4[wc * 256 + rl] = bv[rb * 4 + r];
                    i4[wc * 256 + rl] = bc[rb * 4 + r];
                }
        }
        __syncthreads();
        if (t < 256) {
            float b = v4[t]; int bi = i4[t];
            #pragma unroll
            for (int q = 1; q < 4; ++q) {
                float v = v4[q * 256 + t]; int id = i4[q * 256 + t];
                if (v > b) { b = v; bi = id; }
            }
            pmax[(size_t)blockIdx.y * NP + n0 + t] = b;
            pidx[(size_t)blockIdx.y * NP + n0 + t] = bi;
        }
    }
}

// ---------------- Kernel 3: reduce 36 tile partials -> nn_idx -------------
// 144 blocks x 256 threads: 4 threads/row scan 9 slots each, LDS combine.
__global__ __launch_bounds__(256) void kred(
    const float* __restrict__ pmax, const int* __restrict__ pidx,
    int* __restrict__ nn)
{
    __shared__ float cv[4][64];
    __shared__ int   ci[4][64];

    const int t = threadIdx.x;
    const int n = blockIdx.x * 64 + (t & 63);
    const int p = t >> 6;

    float b = -INFINITY;
    int bi = 0x7fffffff;
    #pragma unroll 3
    for (int c = p * 9; c < p * 9 + 9; ++c) {
        float v = pmax[(size_t)c * NP + n];
        int  id = pidx[(size_t)c * NP + n];
        if (v > b || (v == b && id < bi)) { b = v; bi = id; }
    }
    cv[p][t & 63] = b;
    ci[p][t & 63] = bi;
    __syncthreads();
    if (t < 64) {
        b = cv[0][t]; bi = ci[0][t];
        #pragma unroll
        for (int q = 1; q < 4; ++q) {
            float v = cv[q][t]; int id = ci[q][t];
            if (v > b || (v == b && id < bi)) { b = v; bi = id; }
        }
        nn[blockIdx.x * 64 + t] = bi;
    }
}

// ---------------- Kernel 4: gather Y_sel + fused MSE loss ----------------
// y = H*2^-8 + L*2^-19 (<=6e-8 from exact fp32). k-major plane layout.
__global__ __launch_bounds__(256) void kgather(
    const unsigned short* __restrict__ YH, const unsigned short* __restrict__ YL,
    const int* __restrict__ nn,
    const float* __restrict__ Xf, float* __restrict__ Ysel,
    float* __restrict__ lacc)
{
    __shared__ float tile[64][65];
    __shared__ int   idxs[64];
    __shared__ float wsum[4];

    const int n0 = blockIdx.x * 64;
    const int d0 = blockIdx.y * 64;
    const int tid = threadIdx.x;

    if (tid < 64) idxs[tid] = nn[n0 + tid];
    __syncthreads();

    const int c  = tid & 63;
    const int r0 = tid >> 6;

    #pragma unroll
    for (int s = 0; s < 16; ++s) {
        int r = s * 4 + r0;
        int d = d0 + c;
        size_t off = (size_t)(d >> 5) * KCH + (size_t)idxs[r] * 32 + (d & 31);
        tile[r][c] = h2f(YH[off]) * (1.0f / 256.0f)
                   + h2f(YL[off]) * (1.0f / 524288.0f);   // 2^-19
    }
    __syncthreads();

    float lsum = 0.0f;
    #pragma unroll
    for (int s = 0; s < 16; ++s) {
        int a = s * 4 + r0;
        int d = d0 + a;
        int n = n0 + c;
        float y = tile[c][a];          // stride-65: conflict-free
        float x = Xf[(size_t)d * NP + n];
        float diff = x - y;
        lsum = fmaf(diff, diff, lsum);
        Ysel[(size_t)d * NP + n] = y;  // coalesced over n
    }

    #pragma unroll
    for (int off = 32; off >= 1; off >>= 1)
        lsum += __shfl_xor(lsum, off, 64);
    if ((tid & 63) == 0) wsum[tid >> 6] = lsum;
    __syncthreads();
    if (tid == 0)
        atomicAdd(lacc, wsum[0] + wsum[1] + wsum[2] + wsum[3]);
}

// ---------------- Kernel 5: finalize loss ----------------
__global__ void kfin(const float* __restrict__ lacc, float* __restrict__ out)
{
    out[0] = lacc[0] * (1.0f / (float)DN);
}

extern "C" void kernel_launch(void* const* d_in, const int* in_sizes, int n_in,
                              void* d_out, int out_size, void* d_ws, size_t ws_size,
                              hipStream_t stream)
{
    const float* X = (const float*)d_in[0];   // X_features [1,256,96,96]
    const float* Y = (const float*)d_in[1];   // Y_features [1,256,96,96]
    // d_in[2], d_in[3] (images) are dead code in the reference — unused.

    float* out = (float*)d_out;
    float* Ysel_out = out + 1;          // output 1: Y_sel [1,D,N]
    float* Xf_out   = out + 1 + DN;     // output 2: Xf   [1,D,N]  (exact fp32)

    // Workspace (~21 MB)
    unsigned short* XH = (unsigned short*)d_ws;   // DN halves each
    unsigned short* XL = XH + DN;
    unsigned short* YH = XL + DN;
    unsigned short* YL = YH + DN;
    float* pmax = (float*)(YL + DN);                 // NTT*NP
    int*   pidx = (int*)(pmax + (size_t)NTT * NP);   // NTT*NP
    int*   nn   = pidx + (size_t)NTT * NP;           // NP
    float* lacc = (float*)(nn + NP);                 // 1

    // allow >64 KB dynamic LDS (idempotent host-side call; capture-safe)
    (void)hipFuncSetAttribute((const void*)ksim,
                              hipFuncAttributeMaxDynamicSharedMemorySize,
                              131072);

    hipLaunchKernelGGL(kprep, dim3(NP / 64, 2), dim3(256), 0, stream,
                       X, Y, Xf_out, XH, XL, YH, YL, lacc);
    hipLaunchKernelGGL(ksim, dim3(NTT, NTT), dim3(1024), 131072, stream,
                       XH, XL, YH, YL, pmax, pidx);
    hipLaunchKernelGGL(kred, dim3(NP / 64), dim3(256), 0, stream,
                       pmax, pidx, nn);
    hipLaunchKernelGGL(kgather, dim3(NP / 64, DC / 64), dim3(256), 0, stream,
                       YH, YL, nn, Xf_out, Ysel_out, lacc);
    hipLaunchKernelGGL(kfin, dim3(1), dim3(1), 0, stream, lacc, out);
}